// Round 6
// baseline (11633.592 us; speedup 1.0000x reference)
//
#include <hip/hip_runtime.h>
#include <hip/hip_bf16.h>

typedef __hip_bfloat16 bf16;

#define BM 64
#define BN 64
#define BK 16

__device__ __forceinline__ float b2f(bf16 v) { return __bfloat162float(v); }
__device__ __forceinline__ float sigm(float x) { return 1.0f / (1.0f + __expf(-x)); }

// h[n,c] = bf16(emb[x[n], c])
__global__ __launch_bounds__(256) void k_embed(const int* __restrict__ x,
                                               const float* __restrict__ emb,
                                               bf16* __restrict__ h, int N, int H) {
  int idx = blockIdx.x * 256 + threadIdx.x;
  if (idx >= N * H) return;
  int n = idx / H, c = idx - n * H;
  h[idx] = __float2bfloat16(emb[(size_t)x[n] * H + c]);
}

__global__ __launch_bounds__(256) void k_zero(float4* __restrict__ p, int n4) {
  int i = blockIdx.x * 256 + threadIdx.x;
  if (i < n4) p[i] = make_float4(0.f, 0.f, 0.f, 0.f);
}

// C[M,Nc] = A[M,K] @ W[K,Nc]   (A bf16, W fp32, C bf16, fp32 acc)
__global__ __launch_bounds__(256) void k_gemm_m(const bf16* __restrict__ A,
                                                const float* __restrict__ W,
                                                bf16* __restrict__ C,
                                                int M, int K, int Nc) {
  __shared__ float As[BK][BM + 4];
  __shared__ float Bs[BK][BN + 4];
  int bm = blockIdx.x * BM, bn = blockIdx.y * BN;
  int tid = threadIdx.x;
  int row0 = (tid >> 4) * 4, col0 = (tid & 15) * 4;
  float acc[4][4] = {};
  for (int kt = 0; kt < K; kt += BK) {
#pragma unroll
    for (int i = 0; i < 4; i++) {
      int r = (tid >> 4) + i * 16, c = tid & 15;
      int gr = bm + r, gk = kt + c;
      As[c][r] = (gr < M && gk < K) ? b2f(A[(size_t)gr * K + gk]) : 0.f;
    }
#pragma unroll
    for (int i = 0; i < 4; i++) {
      int k = (tid >> 6) + i * 4, j = tid & 63;
      int gk = kt + k, gj = bn + j;
      Bs[k][j] = (gk < K && gj < Nc) ? W[(size_t)gk * Nc + gj] : 0.f;
    }
    __syncthreads();
#pragma unroll
    for (int k = 0; k < BK; k++) {
      float a[4], b[4];
#pragma unroll
      for (int i = 0; i < 4; i++) a[i] = As[k][row0 + i];
#pragma unroll
      for (int i = 0; i < 4; i++) b[i] = Bs[k][col0 + i];
#pragma unroll
      for (int i = 0; i < 4; i++)
#pragma unroll
        for (int j = 0; j < 4; j++) acc[i][j] += a[i] * b[j];
    }
    __syncthreads();
  }
#pragma unroll
  for (int i = 0; i < 4; i++) {
    int gr = bm + row0 + i;
    if (gr >= M) continue;
#pragma unroll
    for (int j = 0; j < 4; j++) {
      int gj = bn + col0 + j;
      if (gj < Nc) C[(size_t)gr * Nc + gj] = __float2bfloat16(acc[i][j]);
    }
  }
}

// agg[dst[e],:] += m[src[e],:] * ew[e]
__global__ __launch_bounds__(256) void k_scatter(const int* __restrict__ ei,
                                                 const float* __restrict__ ew,
                                                 const bf16* __restrict__ m,
                                                 float* __restrict__ agg,
                                                 int E, int H) {
  int e = blockIdx.x;
  int s = ei[e];
  int d = ei[E + e];
  float w = ew[e];
  for (int j = threadIdx.x; j < H; j += 256)
    atomicAdd(&agg[(size_t)d * H + j], b2f(m[(size_t)s * H + j]) * w);
}

// fused GRU cell: gi = agg@w_ih^T + b_ih ; gh = h@w_hh^T + b_hh ; gates ; h_new
__global__ __launch_bounds__(256) void k_gru(const float* __restrict__ agg,
                                             const bf16* __restrict__ h,
                                             const float* __restrict__ w_ih,
                                             const float* __restrict__ w_hh,
                                             const float* __restrict__ b_ih,
                                             const float* __restrict__ b_hh,
                                             bf16* __restrict__ hn,
                                             int M, int H) {
  __shared__ float As[BK][BM + 4];
  __shared__ float Hs[BK][BM + 4];
  __shared__ float Wi[3][BK][BN + 4];
  __shared__ float Wh[3][BK][BN + 4];
  int bm = blockIdx.x * BM, bn = blockIdx.y * BN;
  int tid = threadIdx.x;
  int row0 = (tid >> 4) * 4, col0 = (tid & 15) * 4;
  float Air[4][4] = {}, Aiz[4][4] = {}, Ain[4][4] = {};
  float Ahr[4][4] = {}, Ahz[4][4] = {}, Ahn[4][4] = {};
  for (int kt = 0; kt < H; kt += BK) {
#pragma unroll
    for (int i = 0; i < 4; i++) {
      int r = (tid >> 4) + i * 16, c = tid & 15;
      int gr = bm + r, gk = kt + c;
      bool ok = (gr < M && gk < H);
      As[c][r] = ok ? agg[(size_t)gr * H + gk] : 0.f;
      Hs[c][r] = ok ? b2f(h[(size_t)gr * H + gk]) : 0.f;
    }
#pragma unroll
    for (int t = 0; t < 3; t++) {
#pragma unroll
      for (int p = 0; p < 4; p++) {
        int j = (tid >> 4) + p * 16, k = tid & 15;
        int gj = bn + j, gk = kt + k;
        bool ok = (gj < H && gk < H);
        Wi[t][k][j] = ok ? w_ih[(size_t)(t * H + gj) * H + gk] : 0.f;
        Wh[t][k][j] = ok ? w_hh[(size_t)(t * H + gj) * H + gk] : 0.f;
      }
    }
    __syncthreads();
#pragma unroll
    for (int k = 0; k < BK; k++) {
      float a[4], hh[4];
#pragma unroll
      for (int i = 0; i < 4; i++) { a[i] = As[k][row0 + i]; hh[i] = Hs[k][row0 + i]; }
#pragma unroll
      for (int j = 0; j < 4; j++) {
        float wir = Wi[0][k][col0 + j], wiz = Wi[1][k][col0 + j], win = Wi[2][k][col0 + j];
        float whr = Wh[0][k][col0 + j], whz = Wh[1][k][col0 + j], whn = Wh[2][k][col0 + j];
#pragma unroll
        for (int i = 0; i < 4; i++) {
          Air[i][j] += a[i] * wir;
          Aiz[i][j] += a[i] * wiz;
          Ain[i][j] += a[i] * win;
          Ahr[i][j] += hh[i] * whr;
          Ahz[i][j] += hh[i] * whz;
          Ahn[i][j] += hh[i] * whn;
        }
      }
    }
    __syncthreads();
  }
#pragma unroll
  for (int j = 0; j < 4; j++) {
    int g = bn + col0 + j;
    if (g >= H) continue;
    float bir = b_ih[g], biz = b_ih[H + g], bin = b_ih[2 * H + g];
    float bhr = b_hh[g], bhz = b_hh[H + g], bhn = b_hh[2 * H + g];
#pragma unroll
    for (int i = 0; i < 4; i++) {
      int row = bm + row0 + i;
      if (row >= M) continue;
      float r = sigm(Air[i][j] + bir + Ahr[i][j] + bhr);
      float z = sigm(Aiz[i][j] + biz + Ahz[i][j] + bhz);
      float n = tanhf(Ain[i][j] + bin + r * (Ahn[i][j] + bhn));
      float hv = b2f(h[(size_t)row * H + g]);
      hn[(size_t)row * H + g] = __float2bfloat16((1.f - z) * n + z * hv);
    }
  }
}

// out[n,o] = sum_k cat(h[gidx[n]], enc[n])[k] * out_w[o,k] + out_b[o]   (FP32 out)
__global__ __launch_bounds__(256) void k_out_naive(const bf16* __restrict__ h,
                                                   const int* __restrict__ gidx,
                                                   const float* __restrict__ enc,
                                                   const float* __restrict__ out_w,
                                                   const float* __restrict__ out_b,
                                                   float* __restrict__ out,
                                                   int H, int OUT) {
  extern __shared__ float cat[];
  int n = blockIdx.x;
  int gid = gidx[n];
  for (int j = threadIdx.x; j < H; j += 256) {
    cat[j]     = b2f(h[(size_t)gid * H + j]);
    cat[H + j] = enc[(size_t)n * H + j];
  }
  __syncthreads();
  int K2 = 2 * H;
  for (int o = threadIdx.x; o < OUT; o += 256) {
    float acc = out_b[o];
    const float* wrow = out_w + (size_t)o * K2;
    for (int k = 0; k < K2; k++) acc += cat[k] * wrow[k];
    out[(size_t)n * OUT + o] = acc;
  }
}

static inline size_t alg(size_t x) { return (x + 255) & ~(size_t)255; }
static inline int cdiv(int a, int b) { return (a + b - 1) / b; }

extern "C" void kernel_launch(void* const* d_in, const int* in_sizes, int n_in,
                              void* d_out, int out_size, void* d_ws, size_t ws_size,
                              hipStream_t stream) {
  (void)out_size; (void)ws_size;
  int s = (n_in >= 14) ? 0 : -1;   // mask (index 4) may be absent
  const int*   x     = (const int*)d_in[0];
  const int*   ei    = (const int*)d_in[1];
  const float* ew    = (const float*)d_in[2];
  const int*   gidx  = (const int*)d_in[3];
  const float* enc   = (const float*)d_in[5 + s];
  const float* emb   = (const float*)d_in[6 + s];
  const float* ggcw  = (const float*)d_in[7 + s];
  const float* w_ih  = (const float*)d_in[8 + s];
  const float* w_hh  = (const float*)d_in[9 + s];
  const float* b_ih  = (const float*)d_in[10 + s];
  const float* b_hh  = (const float*)d_in[11 + s];
  const float* out_w = (const float*)d_in[12 + s];
  const float* out_b = (const float*)d_in[13 + s];
  float* out = (float*)d_out;      // reference output dtype is float32

  // runtime shapes
  int N   = in_sizes[0];
  int E   = in_sizes[2];
  int BL  = in_sizes[3];
  int H   = in_sizes[5 + s] / BL;
  int LG  = in_sizes[7 + s] / (H * H);
  int OUT = in_sizes[12 + s] / (2 * H);

  // workspace: h ping (bf16), h pong (bf16), agg (fp32)
  size_t nh = (size_t)N * H;
  char* p = (char*)d_ws;
  bf16* hA = (bf16*)p;
  bf16* hB = (bf16*)(p + alg(nh * sizeof(bf16)));
  float* agg = (float*)(p + alg(nh * sizeof(bf16)) + alg(nh * sizeof(bf16)));

  k_embed<<<cdiv(N * H, 256), 256, 0, stream>>>(x, emb, hA, N, H);

  dim3 gg(cdiv(N, BM), cdiv(H, BN));
  bf16* h = hA;
  bf16* scr = hB;
  for (int l = 0; l < LG; l++) {
    k_gemm_m<<<gg, 256, 0, stream>>>(h, ggcw + (size_t)l * H * H, scr, N, H, H);
    int n4 = (int)(nh / 4);
    k_zero<<<cdiv(n4, 256), 256, 0, stream>>>((float4*)agg, n4);
    k_scatter<<<E, 256, 0, stream>>>(ei, ew, scr, agg, E, H);
    k_gru<<<gg, 256, 0, stream>>>(agg, h, w_ih, w_hh, b_ih, b_hh, scr, N, H);
    bf16* t = h; h = scr; scr = t;
  }
  k_out_naive<<<BL, 256, 2 * H * sizeof(float), stream>>>(h, gidx, enc, out_w, out_b, out, H, OUT);
}

// Round 7
// 2783.885 us; speedup vs baseline: 4.1789x; 4.1789x over previous
//
#include <hip/hip_runtime.h>
#include <hip/hip_bf16.h>

typedef __hip_bfloat16 bf16;
typedef __attribute__((ext_vector_type(8))) short s8v;   // 8 bf16 = 4 VGPR
typedef __attribute__((ext_vector_type(4))) float f4v;   // MFMA accumulator

#define MFMA16(a, b, c) __builtin_amdgcn_mfma_f32_16x16x32_bf16((a), (b), (c), 0, 0, 0)

__device__ __forceinline__ float b2f(bf16 v) { return __bfloat162float(v); }
__device__ __forceinline__ float sigm(float x) { return 1.0f / (1.0f + __expf(-x)); }

// ---------------- small utility kernels ----------------
__global__ __launch_bounds__(256) void k_cast(const float* __restrict__ s,
                                              bf16* __restrict__ d, int n) {
  int i = blockIdx.x * 256 + threadIdx.x;
  if (i < n) d[i] = __float2bfloat16(s[i]);
}

// ggcwT[l][n][k] = ggc_w[l][k][n]
__global__ __launch_bounds__(256) void k_transpose(const float* __restrict__ s,
                                                   bf16* __restrict__ d, int L, int H) {
  int i = blockIdx.x * 256 + threadIdx.x;
  if (i >= L * H * H) return;
  int l = i / (H * H), r = i - l * (H * H);
  int n = r / H, k = r - n * H;
  d[i] = __float2bfloat16(s[(size_t)l * H * H + (size_t)k * H + n]);
}

__global__ __launch_bounds__(256) void k_embed(const int* __restrict__ x,
                                               const float* __restrict__ emb,
                                               bf16* __restrict__ h, int N, int H) {
  int idx = blockIdx.x * 256 + threadIdx.x;
  if (idx >= N * H) return;
  int n = idx / H, c = idx - n * H;
  h[idx] = __float2bfloat16(emb[(size_t)x[n] * H + c]);
}

// catA[r][k] = k<H ? h[gidx[r]][k] : bf16(enc[r][k-H])
__global__ __launch_bounds__(256) void k_cat(const bf16* __restrict__ h,
                                             const int* __restrict__ gidx,
                                             const float* __restrict__ enc,
                                             bf16* __restrict__ catA, int BL, int H) {
  int i = blockIdx.x * 256 + threadIdx.x;
  if (i >= BL * 2 * H) return;
  int r = i / (2 * H), k = i - r * 2 * H;
  catA[i] = (k < H) ? h[(size_t)gidx[r] * H + k]
                    : __float2bfloat16(enc[(size_t)r * H + (k - H)]);
}

// ---------------- CSR build (once per call) ----------------
__global__ __launch_bounds__(256) void k_zero_i32(int* __restrict__ p, int n) {
  int i = blockIdx.x * 256 + threadIdx.x;
  if (i < n) p[i] = 0;
}
__global__ __launch_bounds__(256) void k_hist(const int* __restrict__ ei,
                                              int* __restrict__ deg, int E) {
  int e = blockIdx.x * 256 + threadIdx.x;
  if (e < E) atomicAdd(&deg[ei[E + e]], 1);
}
// single-block exclusive scan of deg[0..N) -> rowptr[0..N]
__global__ __launch_bounds__(256) void k_scan(const int* __restrict__ deg,
                                              int* __restrict__ rowptr, int N) {
  __shared__ int csum[257];
  int t = threadIdx.x;
  int CS = (N + 255) / 256;
  int b0 = t * CS, b1 = min(b0 + CS, N);
  int s = 0;
  for (int i = b0; i < b1; i++) s += deg[i];
  csum[t] = s;
  __syncthreads();
  if (t == 0) {
    int run = 0;
    for (int q = 0; q < 256; q++) { int tmp = csum[q]; csum[q] = run; run += tmp; }
    csum[256] = run;
  }
  __syncthreads();
  int run = csum[t];
  for (int i = b0; i < b1; i++) { rowptr[i] = run; run += deg[i]; }
  if (t == 0) rowptr[N] = csum[256];
}
__global__ __launch_bounds__(256) void k_copy_i32(const int* __restrict__ s,
                                                  int* __restrict__ d, int n) {
  int i = blockIdx.x * 256 + threadIdx.x;
  if (i < n) d[i] = s[i];
}
__global__ __launch_bounds__(256) void k_fill(const int* __restrict__ ei,
                                              int* __restrict__ cursor,
                                              int* __restrict__ eids, int E) {
  int e = blockIdx.x * 256 + threadIdx.x;
  if (e >= E) return;
  int d = ei[E + e];
  int pos = atomicAdd(&cursor[d], 1);
  eids[pos] = e;
}

// deterministic per-dst gather: agg[d][j] = sum_e w[e]*m[src[e]][j]
__global__ __launch_bounds__(256) void k_aggregate(const int* __restrict__ rowptr,
                                                   const int* __restrict__ eids,
                                                   const int* __restrict__ ei,
                                                   const float* __restrict__ ew,
                                                   const bf16* __restrict__ m,
                                                   bf16* __restrict__ agg,
                                                   int E, int H) {
  int d = blockIdx.x;
  int beg = rowptr[d], end = rowptr[d + 1];
  for (int j = threadIdx.x; j < H; j += 256) {
    float acc = 0.f;
    for (int i = beg; i < end; i++) {
      int e = eids[i];
      acc += b2f(m[(size_t)ei[e] * H + j]) * ew[e];
    }
    agg[(size_t)d * H + j] = __float2bfloat16(acc);
  }
}

// ---------------- MFMA GEMM: C[M,Nc] = A[M,K] @ Bt[Nc,K]^T ----------------
// block 256 thr = 4 waves; tile 128x64, BK=32; wave w -> rows [w*32, w*32+32)
template <int OUT_F32>
__global__ __launch_bounds__(256) void k_gemm(const bf16* __restrict__ A,
                                              const bf16* __restrict__ Bt,
                                              void* __restrict__ Cv,
                                              const float* __restrict__ bias,
                                              int M, int K, int Nc) {
  __shared__ short As[128][40];
  __shared__ short Bs[64][40];
  int gm = blockIdx.x * 128, gn = blockIdx.y * 64;
  int tid = threadIdx.x, w = tid >> 6, lane = tid & 63;
  int l15 = lane & 15, koff = (lane >> 4) * 8;
  f4v acc[2][4];
#pragma unroll
  for (int i = 0; i < 2; i++)
#pragma unroll
    for (int j = 0; j < 4; j++) acc[i][j] = (f4v)0.f;

  for (int kt = 0; kt < K; kt += 32) {
#pragma unroll
    for (int c = 0; c < 2; c++) {            // A tile: 512 16B chunks
      int ch = tid + c * 256;
      int row = ch >> 2, seg = ch & 3;
      *(float4*)&As[row][seg * 8] =
          *(const float4*)(A + (size_t)(gm + row) * K + kt + seg * 8);
    }
    {                                        // B tile: 256 chunks
      int row = tid >> 2, seg = tid & 3;
      *(float4*)&Bs[row][seg * 8] =
          *(const float4*)(Bt + (size_t)(gn + row) * K + kt + seg * 8);
    }
    __syncthreads();
    s8v af[2], bf[4];
#pragma unroll
    for (int rt = 0; rt < 2; rt++) af[rt] = *(const s8v*)&As[w * 32 + rt * 16 + l15][koff];
#pragma unroll
    for (int ct = 0; ct < 4; ct++) bf[ct] = *(const s8v*)&Bs[ct * 16 + l15][koff];
#pragma unroll
    for (int rt = 0; rt < 2; rt++)
#pragma unroll
      for (int ct = 0; ct < 4; ct++) acc[rt][ct] = MFMA16(af[rt], bf[ct], acc[rt][ct]);
    __syncthreads();
  }
#pragma unroll
  for (int rt = 0; rt < 2; rt++)
#pragma unroll
    for (int ct = 0; ct < 4; ct++)
#pragma unroll
      for (int r = 0; r < 4; r++) {
        int row = gm + w * 32 + rt * 16 + (lane >> 4) * 4 + r;
        int col = gn + ct * 16 + l15;
        float v = acc[rt][ct][r];
        if (OUT_F32) ((float*)Cv)[(size_t)row * Nc + col] = v + bias[col];
        else         ((bf16*)Cv)[(size_t)row * Nc + col] = __float2bfloat16(v);
      }
}

// ---------------- fused GRU: gi=agg@Wi^T, gh=h@Wh^T, gates, h_new ----------------
// block tile: 128 rows x 16 cols, but covering gate chunks {c, c+H, c+2H} of both GEMMs.
__global__ __launch_bounds__(256) void k_gru_mfma(const bf16* __restrict__ Aagg,
                                                  const bf16* __restrict__ Ah,
                                                  const bf16* __restrict__ Wi,  // [3H][H] bf16
                                                  const bf16* __restrict__ Wh,
                                                  const float* __restrict__ bi,
                                                  const float* __restrict__ bh,
                                                  bf16* __restrict__ hn,
                                                  int M, int H) {
  __shared__ short Aa[128][40];
  __shared__ short Hs[128][40];
  __shared__ short Bs[6][16][40];
  int gm = blockIdx.x * 128, gc = blockIdx.y * 16;
  int tid = threadIdx.x, w = tid >> 6, lane = tid & 63;
  int l15 = lane & 15, koff = (lane >> 4) * 8;
  f4v ai[2][3], ah[2][3];
#pragma unroll
  for (int i = 0; i < 2; i++)
#pragma unroll
    for (int g = 0; g < 3; g++) { ai[i][g] = (f4v)0.f; ah[i][g] = (f4v)0.f; }

  for (int kt = 0; kt < H; kt += 32) {
#pragma unroll
    for (int c = 0; c < 2; c++) {
      int ch = tid + c * 256;
      int row = ch >> 2, seg = ch & 3;
      *(float4*)&Aa[row][seg * 8] =
          *(const float4*)(Aagg + (size_t)(gm + row) * H + kt + seg * 8);
      *(float4*)&Hs[row][seg * 8] =
          *(const float4*)(Ah + (size_t)(gm + row) * H + kt + seg * 8);
    }
    if (tid < 384) {                         // 6 mats x 16 rows x 4 segs
      int mt = tid >> 6, r16 = (tid >> 2) & 15, seg = tid & 3;
      const bf16* Wsrc = (mt < 3) ? Wi : Wh;
      int g = (mt < 3) ? mt : mt - 3;
      *(float4*)&Bs[mt][r16][seg * 8] =
          *(const float4*)(Wsrc + (size_t)(g * H + gc + r16) * H + kt + seg * 8);
    }
    __syncthreads();
    s8v fa[2], fh[2], fb[6];
#pragma unroll
    for (int rt = 0; rt < 2; rt++) {
      fa[rt] = *(const s8v*)&Aa[w * 32 + rt * 16 + l15][koff];
      fh[rt] = *(const s8v*)&Hs[w * 32 + rt * 16 + l15][koff];
    }
#pragma unroll
    for (int mt = 0; mt < 6; mt++) fb[mt] = *(const s8v*)&Bs[mt][l15][koff];
#pragma unroll
    for (int rt = 0; rt < 2; rt++)
#pragma unroll
      for (int g = 0; g < 3; g++) {
        ai[rt][g] = MFMA16(fa[rt], fb[g],     ai[rt][g]);
        ah[rt][g] = MFMA16(fh[rt], fb[3 + g], ah[rt][g]);
      }
    __syncthreads();
  }
  int col = gc + l15;
  float bir = bi[col], biz = bi[H + col], bin = bi[2 * H + col];
  float bhr = bh[col], bhz = bh[H + col], bhn = bh[2 * H + col];
#pragma unroll
  for (int rt = 0; rt < 2; rt++)
#pragma unroll
    for (int r = 0; r < 4; r++) {
      int row = gm + w * 32 + rt * 16 + (lane >> 4) * 4 + r;
      float rr = sigm(ai[rt][0][r] + bir + ah[rt][0][r] + bhr);
      float zz = sigm(ai[rt][1][r] + biz + ah[rt][1][r] + bhz);
      float nn = tanhf(ai[rt][2][r] + bin + rr * (ah[rt][2][r] + bhn));
      float hv = b2f(Ah[(size_t)row * H + col]);
      hn[(size_t)row * H + col] = __float2bfloat16((1.f - zz) * nn + zz * hv);
    }
}

static inline size_t alg(size_t x) { return (x + 255) & ~(size_t)255; }
static inline int cdiv(int a, int b) { return (a + b - 1) / b; }

extern "C" void kernel_launch(void* const* d_in, const int* in_sizes, int n_in,
                              void* d_out, int out_size, void* d_ws, size_t ws_size,
                              hipStream_t stream) {
  (void)out_size; (void)ws_size;
  int s = (n_in >= 14) ? 0 : -1;
  const int*   x     = (const int*)d_in[0];
  const int*   ei    = (const int*)d_in[1];
  const float* ew    = (const float*)d_in[2];
  const int*   gidx  = (const int*)d_in[3];
  const float* enc   = (const float*)d_in[5 + s];
  const float* emb   = (const float*)d_in[6 + s];
  const float* ggcw  = (const float*)d_in[7 + s];
  const float* w_ih  = (const float*)d_in[8 + s];
  const float* w_hh  = (const float*)d_in[9 + s];
  const float* b_ih  = (const float*)d_in[10 + s];
  const float* b_hh  = (const float*)d_in[11 + s];
  const float* out_w = (const float*)d_in[12 + s];
  const float* out_b = (const float*)d_in[13 + s];
  float* out = (float*)d_out;

  int N   = in_sizes[0];
  int E   = in_sizes[2];
  int BL  = in_sizes[3];
  int H   = in_sizes[5 + s] / BL;
  int LG  = in_sizes[7 + s] / (H * H);
  int OUT = in_sizes[12 + s] / (2 * H);

  size_t nh = (size_t)N * H;
  char* p = (char*)d_ws;
  size_t off = 0;
  bf16* wihB  = (bf16*)(p + off); off = alg(off + (size_t)3 * H * H * 2);
  bf16* whhB  = (bf16*)(p + off); off = alg(off + (size_t)3 * H * H * 2);
  bf16* outwB = (bf16*)(p + off); off = alg(off + (size_t)OUT * 2 * H * 2);
  bf16* ggcwT = (bf16*)(p + off); off = alg(off + (size_t)LG * H * H * 2);
  bf16* hA    = (bf16*)(p + off); off = alg(off + nh * 2);
  bf16* hB    = (bf16*)(p + off); off = alg(off + nh * 2);
  bf16* mbuf  = (bf16*)(p + off); off = alg(off + nh * 2);
  bf16* aggB  = (bf16*)(p + off); off = alg(off + nh * 2);
  bf16* catA  = (bf16*)(p + off); off = alg(off + (size_t)BL * 2 * H * 2);
  int* deg    = (int*)(p + off);  off = alg(off + (size_t)N * 4);
  int* rowptr = (int*)(p + off);  off = alg(off + (size_t)(N + 1) * 4);
  int* cursor = (int*)(p + off);  off = alg(off + (size_t)N * 4);
  int* eids   = (int*)(p + off);  off = alg(off + (size_t)E * 4);

  // weight prep
  k_cast<<<cdiv(3 * H * H, 256), 256, 0, stream>>>(w_ih, wihB, 3 * H * H);
  k_cast<<<cdiv(3 * H * H, 256), 256, 0, stream>>>(w_hh, whhB, 3 * H * H);
  k_cast<<<cdiv(OUT * 2 * H, 256), 256, 0, stream>>>(out_w, outwB, OUT * 2 * H);
  k_transpose<<<cdiv(LG * H * H, 256), 256, 0, stream>>>(ggcw, ggcwT, LG, H);

  // embedding + CSR build
  k_embed<<<cdiv(N * H, 256), 256, 0, stream>>>(x, emb, hA, N, H);
  k_zero_i32<<<cdiv(N, 256), 256, 0, stream>>>(deg, N);
  k_hist<<<cdiv(E, 256), 256, 0, stream>>>(ei, deg, E);
  k_scan<<<1, 256, 0, stream>>>(deg, rowptr, N);
  k_copy_i32<<<cdiv(N, 256), 256, 0, stream>>>(rowptr, cursor, N);
  k_fill<<<cdiv(E, 256), 256, 0, stream>>>(ei, cursor, eids, E);

  bf16* h = hA;
  bf16* hn = hB;
  for (int l = 0; l < LG; l++) {
    k_gemm<0><<<dim3(N / 128, H / 64), 256, 0, stream>>>(
        h, ggcwT + (size_t)l * H * H, mbuf, nullptr, N, H, H);
    k_aggregate<<<N, 256, 0, stream>>>(rowptr, eids, ei, ew, mbuf, aggB, E, H);
    k_gru_mfma<<<dim3(N / 128, H / 16), 256, 0, stream>>>(
        aggB, h, wihB, whhB, b_ih, b_hh, hn, N, H);
    bf16* t = h; h = hn; hn = t;
  }
  k_cat<<<cdiv(BL * 2 * H, 256), 256, 0, stream>>>(h, gidx, enc, catA, BL, H);
  k_gemm<1><<<dim3(BL / 128, OUT / 64), 256, 0, stream>>>(
      catA, outwB, out, out_b, BL, 2 * H, OUT);
}

// Round 9
// 1681.365 us; speedup vs baseline: 6.9191x; 1.6557x over previous
//
#include <hip/hip_runtime.h>
#include <hip/hip_bf16.h>

typedef __hip_bfloat16 bf16;
typedef unsigned short u16;
typedef __attribute__((ext_vector_type(8))) short s8v;   // 8 bf16 = 4 VGPR
typedef __attribute__((ext_vector_type(4))) float f4v;   // MFMA accumulator

#define MFMA16(a, b, c) __builtin_amdgcn_mfma_f32_16x16x32_bf16((a), (b), (c), 0, 0, 0)

__device__ __forceinline__ float b2f(bf16 v) { return __bfloat162float(v); }
__device__ __forceinline__ float sigm(float x) { return 1.0f / (1.0f + __expf(-x)); }
__device__ __forceinline__ float u2f(u16 u) {
  union { float f; unsigned int i; } v; v.i = ((unsigned int)u) << 16; return v.f;
}
__device__ __forceinline__ u16 f2u(float f) {
  bf16 b = __float2bfloat16(f);
  union { bf16 b; u16 u; } v; v.b = b; return v.u;
}

// ---------------- small utility kernels ----------------
__global__ __launch_bounds__(256) void k_cast(const float* __restrict__ s,
                                              bf16* __restrict__ d, int n) {
  int i = blockIdx.x * 256 + threadIdx.x;
  if (i < n) d[i] = __float2bfloat16(s[i]);
}

__global__ __launch_bounds__(256) void k_embed(const int* __restrict__ x,
                                               const float* __restrict__ emb,
                                               bf16* __restrict__ h, int N, int H) {
  int idx = blockIdx.x * 256 + threadIdx.x;
  if (idx >= N * H) return;
  int n = idx / H, c = idx - n * H;
  h[idx] = __float2bfloat16(emb[(size_t)x[n] * H + c]);
}

// catA[r][k] = k<H ? h[gidx[r]][k] : bf16(enc[r][k-H])
__global__ __launch_bounds__(256) void k_cat(const bf16* __restrict__ h,
                                             const int* __restrict__ gidx,
                                             const float* __restrict__ enc,
                                             bf16* __restrict__ catA, int BL, int H) {
  int i = blockIdx.x * 256 + threadIdx.x;
  if (i >= BL * 2 * H) return;
  int r = i / (2 * H), k = i - r * 2 * H;
  catA[i] = (k < H) ? h[(size_t)gidx[r] * H + k]
                    : __float2bfloat16(enc[(size_t)r * H + (k - H)]);
}

// ---------------- CSR build (once per call) ----------------
__global__ __launch_bounds__(256) void k_zero_i32(int* __restrict__ p, int n) {
  int i = blockIdx.x * 256 + threadIdx.x;
  if (i < n) p[i] = 0;
}
__global__ __launch_bounds__(256) void k_hist(const int* __restrict__ ei,
                                              int* __restrict__ deg, int E) {
  int e = blockIdx.x * 256 + threadIdx.x;
  if (e < E) atomicAdd(&deg[ei[E + e]], 1);
}
__global__ __launch_bounds__(256) void k_scan(const int* __restrict__ deg,
                                              int* __restrict__ rowptr, int N) {
  __shared__ int csum[257];
  int t = threadIdx.x;
  int CS = (N + 255) / 256;
  int b0 = t * CS, b1 = min(b0 + CS, N);
  int s = 0;
  for (int i = b0; i < b1; i++) s += deg[i];
  csum[t] = s;
  __syncthreads();
  if (t == 0) {
    int run = 0;
    for (int q = 0; q < 256; q++) { int tmp = csum[q]; csum[q] = run; run += tmp; }
    csum[256] = run;
  }
  __syncthreads();
  int run = csum[t];
  for (int i = b0; i < b1; i++) { rowptr[i] = run; run += deg[i]; }
  if (t == 0) rowptr[N] = csum[256];
}
__global__ __launch_bounds__(256) void k_copy_i32(const int* __restrict__ s,
                                                  int* __restrict__ d, int n) {
  int i = blockIdx.x * 256 + threadIdx.x;
  if (i < n) d[i] = s[i];
}
// CSR-ordered src & weight arrays (removes eids->ei indirection in the hot loop)
__global__ __launch_bounds__(256) void k_fill(const int* __restrict__ ei,
                                              const float* __restrict__ ew,
                                              int* __restrict__ cursor,
                                              int* __restrict__ srcs,
                                              float* __restrict__ wts, int E) {
  int e = blockIdx.x * 256 + threadIdx.x;
  if (e >= E) return;
  int d = ei[E + e];
  int pos = atomicAdd(&cursor[d], 1);
  srcs[pos] = ei[e];
  wts[pos] = ew[e];
}

// sh[d][:] = sum_e wts[e] * h[srcs[e]][:]   — one wave per dst row,
// lane covers 4 cols (ushort4), edge loop unrolled x4 for memory-level parallelism
__global__ __launch_bounds__(256) void k_aggregate(const int* __restrict__ rowptr,
                                                   const int* __restrict__ srcs,
                                                   const float* __restrict__ wts,
                                                   const bf16* __restrict__ hsrc,
                                                   bf16* __restrict__ sh,
                                                   int N, int H) {
  int wv = threadIdx.x >> 6, lane = threadIdx.x & 63;
  int d = blockIdx.x * 4 + wv;
  if (d >= N) return;
  int beg = rowptr[d], end = rowptr[d + 1];
  const u16* hp = (const u16*)hsrc;
  for (int c0 = lane * 4; c0 < H; c0 += 256) {
    float a0 = 0.f, a1 = 0.f, a2 = 0.f, a3 = 0.f;
    int i = beg;
    for (; i + 4 <= end; i += 4) {
      int s0 = srcs[i], s1 = srcs[i + 1], s2 = srcs[i + 2], s3 = srcs[i + 3];
      float w0 = wts[i], w1 = wts[i + 1], w2 = wts[i + 2], w3 = wts[i + 3];
      ushort4 r0 = *(const ushort4*)(hp + (size_t)s0 * H + c0);
      ushort4 r1 = *(const ushort4*)(hp + (size_t)s1 * H + c0);
      ushort4 r2 = *(const ushort4*)(hp + (size_t)s2 * H + c0);
      ushort4 r3 = *(const ushort4*)(hp + (size_t)s3 * H + c0);
      a0 += w0 * u2f(r0.x) + w1 * u2f(r1.x) + w2 * u2f(r2.x) + w3 * u2f(r3.x);
      a1 += w0 * u2f(r0.y) + w1 * u2f(r1.y) + w2 * u2f(r2.y) + w3 * u2f(r3.y);
      a2 += w0 * u2f(r0.z) + w1 * u2f(r1.z) + w2 * u2f(r2.z) + w3 * u2f(r3.z);
      a3 += w0 * u2f(r0.w) + w1 * u2f(r1.w) + w2 * u2f(r2.w) + w3 * u2f(r3.w);
    }
    for (; i < end; i++) {
      int s0 = srcs[i];
      float w0 = wts[i];
      ushort4 r0 = *(const ushort4*)(hp + (size_t)s0 * H + c0);
      a0 += w0 * u2f(r0.x); a1 += w0 * u2f(r0.y);
      a2 += w0 * u2f(r0.z); a3 += w0 * u2f(r0.w);
    }
    ushort4 o;
    o.x = f2u(a0); o.y = f2u(a1); o.z = f2u(a2); o.w = f2u(a3);
    *(ushort4*)((u16*)sh + (size_t)d * H + c0) = o;
  }
}

// ---------------- MFMA GEMM: C[M,Nc] = A[M,K] @ Bt[Nc,K]^T ----------------
template <int OUT_F32>
__global__ __launch_bounds__(256) void k_gemm(const bf16* __restrict__ A,
                                              const bf16* __restrict__ Bt,
                                              void* __restrict__ Cv,
                                              const float* __restrict__ bias,
                                              int M, int K, int Nc) {
  __shared__ short As[128][40];
  __shared__ short Bs[64][40];
  int gm = blockIdx.x * 128, gn = blockIdx.y * 64;
  int tid = threadIdx.x, w = tid >> 6, lane = tid & 63;
  int l15 = lane & 15, koff = (lane >> 4) * 8;
  f4v acc[2][4];
#pragma unroll
  for (int i = 0; i < 2; i++)
#pragma unroll
    for (int j = 0; j < 4; j++) acc[i][j] = (f4v)0.f;

  for (int kt = 0; kt < K; kt += 32) {
#pragma unroll
    for (int c = 0; c < 2; c++) {
      int ch = tid + c * 256;
      int row = ch >> 2, seg = ch & 3;
      *(float4*)&As[row][seg * 8] =
          *(const float4*)(A + (size_t)(gm + row) * K + kt + seg * 8);
    }
    {
      int row = tid >> 2, seg = tid & 3;
      *(float4*)&Bs[row][seg * 8] =
          *(const float4*)(Bt + (size_t)(gn + row) * K + kt + seg * 8);
    }
    __syncthreads();
    s8v af[2], bf[4];
#pragma unroll
    for (int rt = 0; rt < 2; rt++) af[rt] = *(const s8v*)&As[w * 32 + rt * 16 + l15][koff];
#pragma unroll
    for (int ct = 0; ct < 4; ct++) bf[ct] = *(const s8v*)&Bs[ct * 16 + l15][koff];
#pragma unroll
    for (int rt = 0; rt < 2; rt++)
#pragma unroll
      for (int ct = 0; ct < 4; ct++) acc[rt][ct] = MFMA16(af[rt], bf[ct], acc[rt][ct]);
    __syncthreads();
  }
#pragma unroll
  for (int rt = 0; rt < 2; rt++)
#pragma unroll
    for (int ct = 0; ct < 4; ct++)
#pragma unroll
      for (int r = 0; r < 4; r++) {
        int row = gm + w * 32 + rt * 16 + (lane >> 4) * 4 + r;
        int col = gn + ct * 16 + l15;
        float v = acc[rt][ct][r];
        if (OUT_F32) ((float*)Cv)[(size_t)row * Nc + col] = v + bias[col];
        else         ((bf16*)Cv)[(size_t)row * Nc + col] = __float2bfloat16(v);
      }
}

// ---------------- fused GRU: gi=sh@Ul^T, gh=h@Wh^T, gates, h_new ----------------
__global__ __launch_bounds__(256) void k_gru_mfma(const bf16* __restrict__ Ash,
                                                  const bf16* __restrict__ Ah,
                                                  const bf16* __restrict__ Wi,  // Ucomb_l [3H][H]
                                                  const bf16* __restrict__ Wh,  // w_hh [3H][H]
                                                  const float* __restrict__ bi,
                                                  const float* __restrict__ bh,
                                                  bf16* __restrict__ hn,
                                                  int M, int H) {
  __shared__ short Aa[128][40];
  __shared__ short Hs[128][40];
  __shared__ short Bs[6][16][40];
  int gm = blockIdx.x * 128, gc = blockIdx.y * 16;
  int tid = threadIdx.x, w = tid >> 6, lane = tid & 63;
  int l15 = lane & 15, koff = (lane >> 4) * 8;
  f4v ai[2][3], ah[2][3];
#pragma unroll
  for (int i = 0; i < 2; i++)
#pragma unroll
    for (int g = 0; g < 3; g++) { ai[i][g] = (f4v)0.f; ah[i][g] = (f4v)0.f; }

  for (int kt = 0; kt < H; kt += 32) {
#pragma unroll
    for (int c = 0; c < 2; c++) {
      int ch = tid + c * 256;
      int row = ch >> 2, seg = ch & 3;
      *(float4*)&Aa[row][seg * 8] =
          *(const float4*)(Ash + (size_t)(gm + row) * H + kt + seg * 8);
      *(float4*)&Hs[row][seg * 8] =
          *(const float4*)(Ah + (size_t)(gm + row) * H + kt + seg * 8);
    }
    // 6 mats x 16 rows x 4 segs = 384 vector loads; 256 threads -> 2 passes.
    // (R8 bug: `if (tid < 384)` left Bs[4..5] = uninitialized LDS -> NaN/luck.)
#pragma unroll
    for (int q = tid; q < 384; q += 256) {
      int mt = q >> 6, r16 = (q >> 2) & 15, seg = q & 3;
      const bf16* Wsrc = (mt < 3) ? Wi : Wh;
      int g = (mt < 3) ? mt : mt - 3;
      *(float4*)&Bs[mt][r16][seg * 8] =
          *(const float4*)(Wsrc + (size_t)(g * H + gc + r16) * H + kt + seg * 8);
    }
    __syncthreads();
    s8v fa[2], fh[2], fb[6];
#pragma unroll
    for (int rt = 0; rt < 2; rt++) {
      fa[rt] = *(const s8v*)&Aa[w * 32 + rt * 16 + l15][koff];
      fh[rt] = *(const s8v*)&Hs[w * 32 + rt * 16 + l15][koff];
    }
#pragma unroll
    for (int mt = 0; mt < 6; mt++) fb[mt] = *(const s8v*)&Bs[mt][l15][koff];
#pragma unroll
    for (int rt = 0; rt < 2; rt++)
#pragma unroll
      for (int g = 0; g < 3; g++) {
        ai[rt][g] = MFMA16(fa[rt], fb[g],     ai[rt][g]);
        ah[rt][g] = MFMA16(fh[rt], fb[3 + g], ah[rt][g]);
      }
    __syncthreads();
  }
  int col = gc + l15;
  float bir = bi[col], biz = bi[H + col], bin = bi[2 * H + col];
  float bhr = bh[col], bhz = bh[H + col], bhn = bh[2 * H + col];
#pragma unroll
  for (int rt = 0; rt < 2; rt++)
#pragma unroll
    for (int r = 0; r < 4; r++) {
      int row = gm + w * 32 + rt * 16 + (lane >> 4) * 4 + r;
      float rr = sigm(ai[rt][0][r] + bir + ah[rt][0][r] + bhr);
      float zz = sigm(ai[rt][1][r] + biz + ah[rt][1][r] + bhz);
      float nn = tanhf(ai[rt][2][r] + bin + rr * (ah[rt][2][r] + bhn));
      float hv = b2f(Ah[(size_t)row * H + col]);
      hn[(size_t)row * H + col] = __float2bfloat16((1.f - zz) * nn + zz * hv);
    }
}

static inline size_t alg(size_t x) { return (x + 255) & ~(size_t)255; }
static inline int cdiv(int a, int b) { return (a + b - 1) / b; }

extern "C" void kernel_launch(void* const* d_in, const int* in_sizes, int n_in,
                              void* d_out, int out_size, void* d_ws, size_t ws_size,
                              hipStream_t stream) {
  (void)out_size; (void)ws_size;
  int s = (n_in >= 14) ? 0 : -1;
  const int*   x     = (const int*)d_in[0];
  const int*   ei    = (const int*)d_in[1];
  const float* ew    = (const float*)d_in[2];
  const int*   gidx  = (const int*)d_in[3];
  const float* enc   = (const float*)d_in[5 + s];
  const float* emb   = (const float*)d_in[6 + s];
  const float* ggcw  = (const float*)d_in[7 + s];
  const float* w_ih  = (const float*)d_in[8 + s];
  const float* w_hh  = (const float*)d_in[9 + s];
  const float* b_ih  = (const float*)d_in[10 + s];
  const float* b_hh  = (const float*)d_in[11 + s];
  const float* out_w = (const float*)d_in[12 + s];
  const float* out_b = (const float*)d_in[13 + s];
  float* out = (float*)d_out;

  int N   = in_sizes[0];
  int E   = in_sizes[2];
  int BL  = in_sizes[3];
  int H   = in_sizes[5 + s] / BL;
  int LG  = in_sizes[7 + s] / (H * H);
  int OUT = in_sizes[12 + s] / (2 * H);

  size_t nh = (size_t)N * H;
  size_t hh3 = (size_t)3 * H * H;
  char* p = (char*)d_ws;
  size_t off = 0;
  bf16* wihB  = (bf16*)(p + off); off = alg(off + hh3 * 2);
  bf16* whhB  = (bf16*)(p + off); off = alg(off + hh3 * 2);
  bf16* outwB = (bf16*)(p + off); off = alg(off + (size_t)OUT * 2 * H * 2);
  bf16* ggcwB = (bf16*)(p + off); off = alg(off + (size_t)LG * H * H * 2);
  bf16* Ucomb = (bf16*)(p + off); off = alg(off + (size_t)LG * hh3 * 2);
  bf16* hA    = (bf16*)(p + off); off = alg(off + nh * 2);
  bf16* hB    = (bf16*)(p + off); off = alg(off + nh * 2);
  bf16* shB   = (bf16*)(p + off); off = alg(off + nh * 2);
  bf16* catA  = (bf16*)(p + off); off = alg(off + (size_t)BL * 2 * H * 2);
  int* deg    = (int*)(p + off);  off = alg(off + (size_t)N * 4);
  int* rowptr = (int*)(p + off);  off = alg(off + (size_t)(N + 1) * 4);
  int* cursor = (int*)(p + off);  off = alg(off + (size_t)N * 4);
  int* srcs   = (int*)(p + off);  off = alg(off + (size_t)E * 4);
  float* wts  = (float*)(p + off); off = alg(off + (size_t)E * 4);

  // weight prep
  k_cast<<<cdiv((int)hh3, 256), 256, 0, stream>>>(w_ih, wihB, (int)hh3);
  k_cast<<<cdiv((int)hh3, 256), 256, 0, stream>>>(w_hh, whhB, (int)hh3);
  k_cast<<<cdiv(OUT * 2 * H, 256), 256, 0, stream>>>(out_w, outwB, OUT * 2 * H);
  k_cast<<<cdiv(LG * H * H, 256), 256, 0, stream>>>(ggcw, ggcwB, LG * H * H);
  // Ucomb_l[c][k] = sum_p w_ih[c][p] * ggcw_l[k][p]   (folds W_l into the gi GEMM)
  for (int l = 0; l < LG; l++)
    k_gemm<0><<<dim3(3 * H / 128, H / 64), 256, 0, stream>>>(
        wihB, ggcwB + (size_t)l * H * H, Ucomb + (size_t)l * hh3, nullptr, 3 * H, H, H);

  // embedding + CSR build
  k_embed<<<cdiv(N * H, 256), 256, 0, stream>>>(x, emb, hA, N, H);
  k_zero_i32<<<cdiv(N, 256), 256, 0, stream>>>(deg, N);
  k_hist<<<cdiv(E, 256), 256, 0, stream>>>(ei, deg, E);
  k_scan<<<1, 256, 0, stream>>>(deg, rowptr, N);
  k_copy_i32<<<cdiv(N, 256), 256, 0, stream>>>(rowptr, cursor, N);
  k_fill<<<cdiv(E, 256), 256, 0, stream>>>(ei, ew, cursor, srcs, wts, E);

  bf16* h = hA;
  bf16* hn = hB;
  for (int l = 0; l < LG; l++) {
    k_aggregate<<<cdiv(N, 4), 256, 0, stream>>>(rowptr, srcs, wts, h, shB, N, H);
    k_gru_mfma<<<dim3(N / 128, H / 16), 256, 0, stream>>>(
        shB, h, Ucomb + (size_t)l * hh3, whhB, b_ih, b_hh, hn, N, H);
    bf16* t = h; h = hn; hn = t;
  }
  k_cat<<<cdiv(BL * 2 * H, 256), 256, 0, stream>>>(h, gidx, enc, catA, BL, H);
  k_gemm<1><<<dim3(BL / 128, OUT / 64), 256, 0, stream>>>(
      catA, outwB, out, out_b, BL, 2 * H, OUT);
}

// Round 10
// 1387.625 us; speedup vs baseline: 8.3838x; 1.2117x over previous
//
#include <hip/hip_runtime.h>
#include <hip/hip_bf16.h>

typedef __hip_bfloat16 bf16;
typedef unsigned short u16;
typedef __attribute__((ext_vector_type(8))) short s8v;   // 8 bf16 = 4 VGPR
typedef __attribute__((ext_vector_type(4))) float f4v;   // MFMA accumulator

#define MFMA16(a, b, c) __builtin_amdgcn_mfma_f32_16x16x32_bf16((a), (b), (c), 0, 0, 0)

__device__ __forceinline__ float b2f(bf16 v) { return __bfloat162float(v); }
__device__ __forceinline__ float sigm(float x) { return 1.0f / (1.0f + __expf(-x)); }
__device__ __forceinline__ float u2f(u16 u) {
  union { float f; unsigned int i; } v; v.i = ((unsigned int)u) << 16; return v.f;
}
__device__ __forceinline__ u16 f2u(float f) {
  bf16 b = __float2bfloat16(f);
  union { bf16 b; u16 u; } v; v.b = b; return v.u;
}

// ---------------- small utility kernels ----------------
__global__ __launch_bounds__(256) void k_cast(const float* __restrict__ s,
                                              bf16* __restrict__ d, int n) {
  int i = blockIdx.x * 256 + threadIdx.x;
  if (i < n) d[i] = __float2bfloat16(s[i]);
}

__global__ __launch_bounds__(256) void k_embed(const int* __restrict__ x,
                                               const float* __restrict__ emb,
                                               bf16* __restrict__ h, int N, int H) {
  int idx = blockIdx.x * 256 + threadIdx.x;
  if (idx >= N * H) return;
  int n = idx / H, c = idx - n * H;
  h[idx] = __float2bfloat16(emb[(size_t)x[n] * H + c]);
}

// catA[r][k] = k<H ? h[gidx[r]][k] : bf16(enc[r][k-H])
__global__ __launch_bounds__(256) void k_cat(const bf16* __restrict__ h,
                                             const int* __restrict__ gidx,
                                             const float* __restrict__ enc,
                                             bf16* __restrict__ catA, int BL, int H) {
  int i = blockIdx.x * 256 + threadIdx.x;
  if (i >= BL * 2 * H) return;
  int r = i / (2 * H), k = i - r * 2 * H;
  catA[i] = (k < H) ? h[(size_t)gidx[r] * H + k]
                    : __float2bfloat16(enc[(size_t)r * H + (k - H)]);
}

// ---------------- CSR build (once per call) ----------------
__global__ __launch_bounds__(256) void k_zero_i32(int* __restrict__ p, int n) {
  int i = blockIdx.x * 256 + threadIdx.x;
  if (i < n) p[i] = 0;
}
__global__ __launch_bounds__(256) void k_hist(const int* __restrict__ ei,
                                              int* __restrict__ deg, int E) {
  int e = blockIdx.x * 256 + threadIdx.x;
  if (e < E) atomicAdd(&deg[ei[E + e]], 1);
}
__global__ __launch_bounds__(256) void k_scan(const int* __restrict__ deg,
                                              int* __restrict__ rowptr, int N) {
  __shared__ int csum[257];
  int t = threadIdx.x;
  int CS = (N + 255) / 256;
  int b0 = t * CS, b1 = min(b0 + CS, N);
  int s = 0;
  for (int i = b0; i < b1; i++) s += deg[i];
  csum[t] = s;
  __syncthreads();
  if (t == 0) {
    int run = 0;
    for (int q = 0; q < 256; q++) { int tmp = csum[q]; csum[q] = run; run += tmp; }
    csum[256] = run;
  }
  __syncthreads();
  int run = csum[t];
  for (int i = b0; i < b1; i++) { rowptr[i] = run; run += deg[i]; }
  if (t == 0) rowptr[N] = csum[256];
}
__global__ __launch_bounds__(256) void k_copy_i32(const int* __restrict__ s,
                                                  int* __restrict__ d, int n) {
  int i = blockIdx.x * 256 + threadIdx.x;
  if (i < n) d[i] = s[i];
}
__global__ __launch_bounds__(256) void k_fill(const int* __restrict__ ei,
                                              const float* __restrict__ ew,
                                              int* __restrict__ cursor,
                                              int* __restrict__ srcs,
                                              float* __restrict__ wts, int E) {
  int e = blockIdx.x * 256 + threadIdx.x;
  if (e >= E) return;
  int d = ei[E + e];
  int pos = atomicAdd(&cursor[d], 1);
  srcs[pos] = ei[e];
  wts[pos] = ew[e];
}

// sh[d][:] = sum_e wts[e] * h[srcs[e]][:]
__global__ __launch_bounds__(256) void k_aggregate(const int* __restrict__ rowptr,
                                                   const int* __restrict__ srcs,
                                                   const float* __restrict__ wts,
                                                   const bf16* __restrict__ hsrc,
                                                   bf16* __restrict__ sh,
                                                   int N, int H) {
  int wv = threadIdx.x >> 6, lane = threadIdx.x & 63;
  int d = blockIdx.x * 4 + wv;
  if (d >= N) return;
  int beg = rowptr[d], end = rowptr[d + 1];
  const u16* hp = (const u16*)hsrc;
  for (int c0 = lane * 4; c0 < H; c0 += 256) {
    float a0 = 0.f, a1 = 0.f, a2 = 0.f, a3 = 0.f;
    int i = beg;
    for (; i + 4 <= end; i += 4) {
      int s0 = srcs[i], s1 = srcs[i + 1], s2 = srcs[i + 2], s3 = srcs[i + 3];
      float w0 = wts[i], w1 = wts[i + 1], w2 = wts[i + 2], w3 = wts[i + 3];
      ushort4 r0 = *(const ushort4*)(hp + (size_t)s0 * H + c0);
      ushort4 r1 = *(const ushort4*)(hp + (size_t)s1 * H + c0);
      ushort4 r2 = *(const ushort4*)(hp + (size_t)s2 * H + c0);
      ushort4 r3 = *(const ushort4*)(hp + (size_t)s3 * H + c0);
      a0 += w0 * u2f(r0.x) + w1 * u2f(r1.x) + w2 * u2f(r2.x) + w3 * u2f(r3.x);
      a1 += w0 * u2f(r0.y) + w1 * u2f(r1.y) + w2 * u2f(r2.y) + w3 * u2f(r3.y);
      a2 += w0 * u2f(r0.z) + w1 * u2f(r1.z) + w2 * u2f(r2.z) + w3 * u2f(r3.z);
      a3 += w0 * u2f(r0.w) + w1 * u2f(r1.w) + w2 * u2f(r2.w) + w3 * u2f(r3.w);
    }
    for (; i < end; i++) {
      int s0 = srcs[i];
      float w0 = wts[i];
      ushort4 r0 = *(const ushort4*)(hp + (size_t)s0 * H + c0);
      a0 += w0 * u2f(r0.x); a1 += w0 * u2f(r0.y);
      a2 += w0 * u2f(r0.z); a3 += w0 * u2f(r0.w);
    }
    ushort4 o;
    o.x = f2u(a0); o.y = f2u(a1); o.z = f2u(a2); o.w = f2u(a3);
    *(ushort4*)((u16*)sh + (size_t)d * H + c0) = o;
  }
}

// ---------------- MFMA GEMM: C[M,Nc] = A[M,K] @ Bt[Nc,K]^T ----------------
template <int OUT_F32>
__global__ __launch_bounds__(256) void k_gemm(const bf16* __restrict__ A,
                                              const bf16* __restrict__ Bt,
                                              void* __restrict__ Cv,
                                              const float* __restrict__ bias,
                                              int M, int K, int Nc) {
  __shared__ short As[128][40];
  __shared__ short Bs[64][40];
  int gm = blockIdx.x * 128, gn = blockIdx.y * 64;
  int tid = threadIdx.x, w = tid >> 6, lane = tid & 63;
  int l15 = lane & 15, koff = (lane >> 4) * 8;
  f4v acc[2][4];
#pragma unroll
  for (int i = 0; i < 2; i++)
#pragma unroll
    for (int j = 0; j < 4; j++) acc[i][j] = (f4v)0.f;

  for (int kt = 0; kt < K; kt += 32) {
#pragma unroll
    for (int c = 0; c < 2; c++) {
      int ch = tid + c * 256;
      int row = ch >> 2, seg = ch & 3;
      *(float4*)&As[row][seg * 8] =
          *(const float4*)(A + (size_t)(gm + row) * K + kt + seg * 8);
    }
    {
      int row = tid >> 2, seg = tid & 3;
      *(float4*)&Bs[row][seg * 8] =
          *(const float4*)(Bt + (size_t)(gn + row) * K + kt + seg * 8);
    }
    __syncthreads();
    s8v af[2], bf[4];
#pragma unroll
    for (int rt = 0; rt < 2; rt++) af[rt] = *(const s8v*)&As[w * 32 + rt * 16 + l15][koff];
#pragma unroll
    for (int ct = 0; ct < 4; ct++) bf[ct] = *(const s8v*)&Bs[ct * 16 + l15][koff];
#pragma unroll
    for (int rt = 0; rt < 2; rt++)
#pragma unroll
      for (int ct = 0; ct < 4; ct++) acc[rt][ct] = MFMA16(af[rt], bf[ct], acc[rt][ct]);
    __syncthreads();
  }
#pragma unroll
  for (int rt = 0; rt < 2; rt++)
#pragma unroll
    for (int ct = 0; ct < 4; ct++)
#pragma unroll
      for (int r = 0; r < 4; r++) {
        int row = gm + w * 32 + rt * 16 + (lane >> 4) * 4 + r;
        int col = gn + ct * 16 + l15;
        float v = acc[rt][ct][r];
        if (OUT_F32) ((float*)Cv)[(size_t)row * Nc + col] = v + bias[col];
        else         ((bf16*)Cv)[(size_t)row * Nc + col] = __float2bfloat16(v);
      }
}

// ---------------- fused GRU, 128x64 tile (4 col-blocks instead of 16) -------
// r,z gates: gi and gh chained into ONE accumulator (sum is all gates need);
// n gate: separate i/h accs (epilogue needs r*(h_n)). 32 f4v accs total.
__global__ __launch_bounds__(256) void k_gru_mfma(const bf16* __restrict__ Ash,
                                                  const bf16* __restrict__ Ah,
                                                  const bf16* __restrict__ Wi,  // Ucomb_l [3H][H]
                                                  const bf16* __restrict__ Wh,  // w_hh [3H][H]
                                                  const float* __restrict__ bi,
                                                  const float* __restrict__ bh,
                                                  bf16* __restrict__ hn,
                                                  int M, int H) {
  __shared__ short Aa[128][40];
  __shared__ short Hs[128][40];
  __shared__ short Bs[6][64][40];
  int gcol = blockIdx.x * 64, gm = blockIdx.y * 128;
  int tid = threadIdx.x, w = tid >> 6, lane = tid & 63;
  int l15 = lane & 15, koff = (lane >> 4) * 8;
  f4v accR[2][4], accZ[2][4], accNi[2][4], accNh[2][4];
#pragma unroll
  for (int rt = 0; rt < 2; rt++)
#pragma unroll
    for (int ct = 0; ct < 4; ct++) {
      accR[rt][ct] = (f4v)0.f; accZ[rt][ct] = (f4v)0.f;
      accNi[rt][ct] = (f4v)0.f; accNh[rt][ct] = (f4v)0.f;
    }

  for (int kt = 0; kt < H; kt += 32) {
#pragma unroll
    for (int c = 0; c < 2; c++) {
      int ch = tid + c * 256;
      int row = ch >> 2, seg = ch & 3;
      *(float4*)&Aa[row][seg * 8] =
          *(const float4*)(Ash + (size_t)(gm + row) * H + kt + seg * 8);
      *(float4*)&Hs[row][seg * 8] =
          *(const float4*)(Ah + (size_t)(gm + row) * H + kt + seg * 8);
    }
#pragma unroll
    for (int q = 0; q < 6; q++) {            // 6 mats x 64 rows x 4 segs
      int r = tid >> 2, seg = tid & 3;
      const bf16* Wsrc = (q < 3) ? Wi : Wh;
      int g = (q < 3) ? q : q - 3;
      *(float4*)&Bs[q][r][seg * 8] =
          *(const float4*)(Wsrc + (size_t)(g * H + gcol + r) * H + kt + seg * 8);
    }
    __syncthreads();
    s8v fa[2], fh[2];
#pragma unroll
    for (int rt = 0; rt < 2; rt++) {
      fa[rt] = *(const s8v*)&Aa[w * 32 + rt * 16 + l15][koff];
      fh[rt] = *(const s8v*)&Hs[w * 32 + rt * 16 + l15][koff];
    }
#pragma unroll
    for (int ct = 0; ct < 4; ct++) {
      s8v bRi = *(const s8v*)&Bs[0][ct * 16 + l15][koff];
      s8v bZi = *(const s8v*)&Bs[1][ct * 16 + l15][koff];
      s8v bNi = *(const s8v*)&Bs[2][ct * 16 + l15][koff];
      s8v bRh = *(const s8v*)&Bs[3][ct * 16 + l15][koff];
      s8v bZh = *(const s8v*)&Bs[4][ct * 16 + l15][koff];
      s8v bNh = *(const s8v*)&Bs[5][ct * 16 + l15][koff];
#pragma unroll
      for (int rt = 0; rt < 2; rt++) {
        accR[rt][ct]  = MFMA16(fa[rt], bRi, accR[rt][ct]);
        accR[rt][ct]  = MFMA16(fh[rt], bRh, accR[rt][ct]);
        accZ[rt][ct]  = MFMA16(fa[rt], bZi, accZ[rt][ct]);
        accZ[rt][ct]  = MFMA16(fh[rt], bZh, accZ[rt][ct]);
        accNi[rt][ct] = MFMA16(fa[rt], bNi, accNi[rt][ct]);
        accNh[rt][ct] = MFMA16(fh[rt], bNh, accNh[rt][ct]);
      }
    }
    __syncthreads();
  }
#pragma unroll
  for (int ct = 0; ct < 4; ct++) {
    int col = gcol + ct * 16 + l15;
    float br  = bi[col] + bh[col];
    float bz  = bi[H + col] + bh[H + col];
    float bin = bi[2 * H + col], bhn = bh[2 * H + col];
#pragma unroll
    for (int rt = 0; rt < 2; rt++)
#pragma unroll
      for (int r = 0; r < 4; r++) {
        int row = gm + w * 32 + rt * 16 + (lane >> 4) * 4 + r;
        float rr = sigm(accR[rt][ct][r] + br);
        float zz = sigm(accZ[rt][ct][r] + bz);
        float nn = tanhf(accNi[rt][ct][r] + bin + rr * (accNh[rt][ct][r] + bhn));
        float hv = b2f(Ah[(size_t)row * H + col]);
        hn[(size_t)row * H + col] = __float2bfloat16((1.f - zz) * nn + zz * hv);
      }
  }
}

static inline size_t alg(size_t x) { return (x + 255) & ~(size_t)255; }
static inline int cdiv(int a, int b) { return (a + b - 1) / b; }

extern "C" void kernel_launch(void* const* d_in, const int* in_sizes, int n_in,
                              void* d_out, int out_size, void* d_ws, size_t ws_size,
                              hipStream_t stream) {
  (void)out_size; (void)ws_size;
  int s = (n_in >= 14) ? 0 : -1;
  const int*   x     = (const int*)d_in[0];
  const int*   ei    = (const int*)d_in[1];
  const float* ew    = (const float*)d_in[2];
  const int*   gidx  = (const int*)d_in[3];
  const float* enc   = (const float*)d_in[5 + s];
  const float* emb   = (const float*)d_in[6 + s];
  const float* ggcw  = (const float*)d_in[7 + s];
  const float* w_ih  = (const float*)d_in[8 + s];
  const float* w_hh  = (const float*)d_in[9 + s];
  const float* b_ih  = (const float*)d_in[10 + s];
  const float* b_hh  = (const float*)d_in[11 + s];
  const float* out_w = (const float*)d_in[12 + s];
  const float* out_b = (const float*)d_in[13 + s];
  float* out = (float*)d_out;

  int N   = in_sizes[0];
  int E   = in_sizes[2];
  int BL  = in_sizes[3];
  int H   = in_sizes[5 + s] / BL;
  int LG  = in_sizes[7 + s] / (H * H);
  int OUT = in_sizes[12 + s] / (2 * H);

  size_t nh = (size_t)N * H;
  size_t hh3 = (size_t)3 * H * H;
  char* p = (char*)d_ws;
  size_t off = 0;
  bf16* wihB  = (bf16*)(p + off); off = alg(off + hh3 * 2);
  bf16* whhB  = (bf16*)(p + off); off = alg(off + hh3 * 2);
  bf16* outwB = (bf16*)(p + off); off = alg(off + (size_t)OUT * 2 * H * 2);
  bf16* ggcwB = (bf16*)(p + off); off = alg(off + (size_t)LG * H * H * 2);
  bf16* Ucomb = (bf16*)(p + off); off = alg(off + (size_t)LG * hh3 * 2);
  bf16* hA    = (bf16*)(p + off); off = alg(off + nh * 2);
  bf16* hB    = (bf16*)(p + off); off = alg(off + nh * 2);
  bf16* shB   = (bf16*)(p + off); off = alg(off + nh * 2);
  bf16* catA  = (bf16*)(p + off); off = alg(off + (size_t)BL * 2 * H * 2);
  int* deg    = (int*)(p + off);  off = alg(off + (size_t)N * 4);
  int* rowptr = (int*)(p + off);  off = alg(off + (size_t)(N + 1) * 4);
  int* cursor = (int*)(p + off);  off = alg(off + (size_t)N * 4);
  int* srcs   = (int*)(p + off);  off = alg(off + (size_t)E * 4);
  float* wts  = (float*)(p + off); off = alg(off + (size_t)E * 4);

  // weight prep
  k_cast<<<cdiv((int)hh3, 256), 256, 0, stream>>>(w_ih, wihB, (int)hh3);
  k_cast<<<cdiv((int)hh3, 256), 256, 0, stream>>>(w_hh, whhB, (int)hh3);
  k_cast<<<cdiv(OUT * 2 * H, 256), 256, 0, stream>>>(out_w, outwB, OUT * 2 * H);
  k_cast<<<cdiv(LG * H * H, 256), 256, 0, stream>>>(ggcw, ggcwB, LG * H * H);
  // Ucomb_l[c][k] = sum_p w_ih[c][p] * ggcw_l[k][p]
  for (int l = 0; l < LG; l++)
    k_gemm<0><<<dim3(3 * H / 128, H / 64), 256, 0, stream>>>(
        wihB, ggcwB + (size_t)l * H * H, Ucomb + (size_t)l * hh3, nullptr, 3 * H, H, H);

  // embedding + CSR build
  k_embed<<<cdiv(N * H, 256), 256, 0, stream>>>(x, emb, hA, N, H);
  k_zero_i32<<<cdiv(N, 256), 256, 0, stream>>>(deg, N);
  k_hist<<<cdiv(E, 256), 256, 0, stream>>>(ei, deg, E);
  k_scan<<<1, 256, 0, stream>>>(deg, rowptr, N);
  k_copy_i32<<<cdiv(N, 256), 256, 0, stream>>>(rowptr, cursor, N);
  k_fill<<<cdiv(E, 256), 256, 0, stream>>>(ei, ew, cursor, srcs, wts, E);

  bf16* h = hA;
  bf16* hn = hB;
  for (int l = 0; l < LG; l++) {
    k_aggregate<<<cdiv(N, 4), 256, 0, stream>>>(rowptr, srcs, wts, h, shB, N, H);
    k_gru_mfma<<<dim3(H / 64, N / 128), 256, 0, stream>>>(
        shB, h, Ucomb + (size_t)l * hh3, whhB, b_ih, b_hh, hn, N, H);
    bf16* t = h; h = hn; hn = t;
  }
  k_cat<<<cdiv(BL * 2 * H, 256), 256, 0, stream>>>(h, gidx, enc, catA, BL, H);
  k_gemm<1><<<dim3(BL / 128, OUT / 64), 256, 0, stream>>>(
      catA, outwB, out, out_b, BL, 2 * H, OUT);
}